// Round 4
// baseline (410.461 us; speedup 1.0000x reference)
//
#include <hip/hip_runtime.h>
#include <hip/hip_bf16.h>

typedef __hip_bfloat16 bf16;
typedef __attribute__((ext_vector_type(8))) short bf16x8;
typedef __attribute__((ext_vector_type(4))) float floatx4;

#define NB 16
#define NC 256
#define NPIX 4096
#define NHID 128
#define NH 4
#define ND 32
#define NMEM 4
#define QSCALE 0.17677669529663687f  // 32^-0.5
#define PXT 512    // px per k3 block
#define PXSUB 128  // px per k3 subtile

__device__ __forceinline__ bf16x8 pack_bf8(const float* f){
  union { bf16x8 v; bf16 e[8]; } u;
  #pragma unroll
  for (int i = 0; i < 8; ++i) u.e[i] = __float2bfloat16(f[i]);
  return u.v;
}

// ---------------- K0: zero the atomic accumulators (ctxu + zacc, contiguous)
__global__ void k0_zero(float* __restrict__ p, int n){
  int i = blockIdx.x*256 + threadIdx.x;
  if (i < n) p[i] = 0.f;
}

// ---------------- K1: per-pixel channel norm scale: s = 16 / max(||x_c||, 1e-12)
__launch_bounds__(256)
__global__ void k1_norm(const float* __restrict__ x, float* __restrict__ s){
  __shared__ float sm[4][64];
  const int t  = threadIdx.x;
  const int px = blockIdx.x * 64 + (t & 63);
  const int cg = t >> 6;
  const int b  = blockIdx.y;
  const float* xp = x + (size_t)b*NC*NPIX + (size_t)cg*64*NPIX + px;
  float acc = 0.f;
  #pragma unroll 8
  for (int c = 0; c < 64; ++c){ float v = xp[(size_t)c*NPIX]; acc += v*v; }
  sm[cg][t & 63] = acc;
  __syncthreads();
  if (cg == 0){
    float tot = sm[0][t] + sm[1][t] + sm[2][t] + sm[3][t];
    s[b*NPIX + px] = 16.0f / fmaxf(sqrtf(tot), 1e-12f);
  }
}

// ---------------- K2: q rows (wqkv[0:128]) and v rows (wqkv[256:384]) -> d_out (fp32)
// dout[b][0:128]   = q[b][hd][px] = s*.(wq g)x   (raw q; softmax happens in K5)
// dout[b][128:256] = v[b][hd][px]
__launch_bounds__(256)
__global__ void k2_qv(const float* __restrict__ x, const float* __restrict__ wqkv,
                      const float* __restrict__ g, const float* __restrict__ s,
                      float* __restrict__ dout){
  __shared__ float As[32][128];   // [k][o]
  __shared__ float Bs[32][128];   // [k][p]
  const int t  = threadIdx.x;
  const int b  = blockIdx.z;
  const int wbase = blockIdx.y ? 256 : 0;   // wqkv row base (q or v block)
  const int rbase = blockIdx.y * 128;       // dout row base
  const int pb = blockIdx.x * 128;
  const int tx = t & 15, ty = t >> 4;
  const int ar = t >> 1,  ac = (t & 1) * 16;
  const int bc = t >> 3,  bp = (t & 7) * 16;
  const float* xb = x + (size_t)b*NC*NPIX;
  float acc[8][8] = {};
  for (int k0 = 0; k0 < NC; k0 += 32){
    {
      const float* wp = wqkv + (size_t)(wbase + ar)*NC + (k0 + ac);
      float wf[16], gf[16];
      #pragma unroll
      for (int q = 0; q < 4; ++q){
        *(floatx4*)&wf[4*q] = *(const floatx4*)(wp + 4*q);
        *(floatx4*)&gf[4*q] = *(const floatx4*)(g + k0 + ac + 4*q);
      }
      #pragma unroll
      for (int i = 0; i < 16; ++i) As[ac + i][ar] = wf[i]*gf[i];
      const float* xp = xb + (size_t)(k0 + bc)*NPIX + pb + bp;
      #pragma unroll
      for (int q = 0; q < 4; ++q)
        *(floatx4*)&Bs[bc][bp + 4*q] = *(const floatx4*)(xp + 4*q);
    }
    __syncthreads();
    #pragma unroll
    for (int kk = 0; kk < 32; ++kk){
      float a[8], bb[8];
      *(floatx4*)&a[0]  = *(const floatx4*)&As[kk][ty*8];
      *(floatx4*)&a[4]  = *(const floatx4*)&As[kk][ty*8 + 4];
      *(floatx4*)&bb[0] = *(const floatx4*)&Bs[kk][tx*8];
      *(floatx4*)&bb[4] = *(const floatx4*)&Bs[kk][tx*8 + 4];
      #pragma unroll
      for (int i = 0; i < 8; ++i)
        #pragma unroll
        for (int j = 0; j < 8; ++j)
          acc[i][j] += a[i]*bb[j];
    }
    __syncthreads();
  }
  float sv[8];
  #pragma unroll
  for (int j = 0; j < 8; ++j) sv[j] = s[b*NPIX + pb + tx*8 + j];
  float* op = dout + (size_t)(b*NC + rbase + ty*8)*NPIX + pb + tx*8;
  #pragma unroll
  for (int i = 0; i < 8; ++i){
    #pragma unroll
    for (int j = 0; j < 8; j += 4){
      floatx4 ov;
      #pragma unroll
      for (int q = 0; q < 4; ++q) ov[q] = acc[i][j+q]*sv[j+q];
      *(floatx4*)(op + (size_t)i*NPIX + j) = ov;
    }
  }
}

// ---------------- K3: fused k-recompute + exp + ctx/z accumulation.
// Per block (h, pxb, b): k[d][px] = s[px]*sum_c (wk[h*32+d][c]*g[c])*x[c][px]
// P = exp(k); ctxu[b][h][d][e] += sum_px P[d][px]*v[e][px];  z[b][hd] += sum_px P
__launch_bounds__(256)
__global__ void k3_ctx(const float* __restrict__ x, const float* __restrict__ wqkv,
                       const float* __restrict__ g, const float* __restrict__ s,
                       const float* __restrict__ dout,
                       float* __restrict__ ctxu, float* __restrict__ zacc){
  __shared__ float Ak[32][257];    // w_k*g, padded (32.9 KB)
  __shared__ float xs[32][132];    // x chunk, padded (16.9 KB)
  __shared__ bf16  Ps[32][136];    // P tile bf16, stride 136 (8.7 KB)
  const int t = threadIdx.x;
  const int h = blockIdx.x, pxb = blockIdx.y, b = blockIdx.z;
  // stage Ak: thread -> d = t>>3, 32 cols from (t&7)*32
  {
    const int d = t >> 3, cs = (t & 7) * 32;
    const float* wp = wqkv + (size_t)(NHID + h*ND + d)*NC + cs;
    #pragma unroll
    for (int q = 0; q < 8; ++q){
      floatx4 w4 = *(const floatx4*)(wp + 4*q);
      floatx4 g4 = *(const floatx4*)(g + cs + 4*q);
      #pragma unroll
      for (int i = 0; i < 4; ++i) Ak[d][cs + 4*q + i] = w4[i]*g4[i];
    }
  }
  const int ty = t >> 4, tx = t & 15;     // producer: d rows {2ty,2ty+1}, px cols tx*8..+8
  const int wv = t >> 6;                  // wave id for MFMA phase
  const int lane = t & 63, m = lane & 15, q4 = lane >> 4;
  const float* xb = x + (size_t)b*NC*NPIX;
  const float* vb = dout + (size_t)b*NC*NPIX + (size_t)(NHID + h*ND)*NPIX;
  floatx4 acc[2][2] = {};
  float z0 = 0.f, z1 = 0.f;
  for (int sub = 0; sub < 4; ++sub){
    const int px0 = pxb*PXT + sub*PXSUB;
    float kacc[2][8] = {};
    for (int c0 = 0; c0 < NC; c0 += 32){
      __syncthreads();   // Ak stage->read (1st iter); xs prev readers -> writers
      {
        const int r = t >> 3, cl = (t & 7) * 16;
        const float* xp = xb + (size_t)(c0 + r)*NPIX + px0 + cl;
        #pragma unroll
        for (int q = 0; q < 4; ++q)
          *(floatx4*)&xs[r][cl + 4*q] = *(const floatx4*)(xp + 4*q);
      }
      __syncthreads();
      #pragma unroll
      for (int cc = 0; cc < 32; ++cc){
        const float a0 = Ak[2*ty    ][c0 + cc];
        const float a1 = Ak[2*ty + 1][c0 + cc];
        float xv[8];
        *(floatx4*)&xv[0] = *(const floatx4*)&xs[cc][tx*8];
        *(floatx4*)&xv[4] = *(const floatx4*)&xs[cc][tx*8 + 4];
        #pragma unroll
        for (int j = 0; j < 8; ++j){
          kacc[0][j] += a0*xv[j];
          kacc[1][j] += a1*xv[j];
        }
      }
    }
    // exp + store P + z partials
    {
      float sv[8];
      *(floatx4*)&sv[0] = *(const floatx4*)(s + b*NPIX + px0 + tx*8);
      *(floatx4*)&sv[4] = *(const floatx4*)(s + b*NPIX + px0 + tx*8 + 4);
      __syncthreads();   // previous sub's MFMA readers of Ps done
      alignas(16) bf16 pk0[8], pk1[8];
      #pragma unroll
      for (int j = 0; j < 8; ++j){
        float p0 = __expf(kacc[0][j]*sv[j]);
        float p1 = __expf(kacc[1][j]*sv[j]);
        z0 += p0; z1 += p1;
        pk0[j] = __float2bfloat16(p0);
        pk1[j] = __float2bfloat16(p1);
      }
      *(uint4*)&Ps[2*ty    ][tx*8] = *(const uint4*)pk0;
      *(uint4*)&Ps[2*ty + 1][tx*8] = *(const uint4*)pk1;
    }
    __syncthreads();
    // MFMA: wave wv handles px chunk wv*32 within this subtile
    {
      const int pxc = wv*32 + q4*8;
      bf16x8 a0 = *(const bf16x8*)&Ps[m][pxc];
      bf16x8 a1 = *(const bf16x8*)&Ps[16 + m][pxc];
      const float* vp = vb + (size_t)m*NPIX + px0 + pxc;
      float vf0[8], vf1[8];
      *(floatx4*)&vf0[0] = *(const floatx4*)vp;
      *(floatx4*)&vf0[4] = *(const floatx4*)(vp + 4);
      *(floatx4*)&vf1[0] = *(const floatx4*)(vp + (size_t)16*NPIX);
      *(floatx4*)&vf1[4] = *(const floatx4*)(vp + (size_t)16*NPIX + 4);
      bf16x8 b0 = pack_bf8(vf0);
      bf16x8 b1 = pack_bf8(vf1);
      acc[0][0] = __builtin_amdgcn_mfma_f32_16x16x32_bf16(a0, b0, acc[0][0], 0, 0, 0);
      acc[0][1] = __builtin_amdgcn_mfma_f32_16x16x32_bf16(a0, b1, acc[0][1], 0, 0, 0);
      acc[1][0] = __builtin_amdgcn_mfma_f32_16x16x32_bf16(a1, b0, acc[1][0], 0, 0, 0);
      acc[1][1] = __builtin_amdgcn_mfma_f32_16x16x32_bf16(a1, b1, acc[1][1], 0, 0, 0);
    }
  }
  // z: reduce over the 16 px-threads of each d-row pair
  #pragma unroll
  for (int o = 8; o > 0; o >>= 1){
    z0 += __shfl_down(z0, o, 16);
    z1 += __shfl_down(z1, o, 16);
  }
  if (tx == 0){
    atomicAdd(&zacc[b*NHID + h*ND + 2*ty    ], z0);
    atomicAdd(&zacc[b*NHID + h*ND + 2*ty + 1], z1);
  }
  // ctx: C/D layout col=lane&15 (e), row=q4*4+r (d)
  float* cb = ctxu + (size_t)(b*NH + h)*ND*ND;
  #pragma unroll
  for (int di = 0; di < 2; ++di)
    #pragma unroll
    for (int ei = 0; ei < 2; ++ei)
      #pragma unroll
      for (int r = 0; r < 4; ++r)
        atomicAdd(&cb[(di*16 + q4*4 + r)*ND + ei*16 + m], acc[di][ei][r]);
}

// ---------------- K4: Weff[b][hd][o] = sum_e wout[o][h*32+e]*ctx_final[b][h][d][e]
// ctx_final = (ctxu + sum_j exp(mk[d][j])*mv[e][j]) / (z[d] + sum_j exp(mk[d][j]))
__launch_bounds__(256)
__global__ void k4_weff(const float* __restrict__ ctxu, const float* __restrict__ zacc,
                        const float* __restrict__ memkv, const float* __restrict__ wout,
                        float* __restrict__ weff){
  const int idx = blockIdx.x*256 + threadIdx.x;   // (b*128+hd)*256 + o
  const int b   = idx >> 15;
  const int rem = idx & 32767;
  const int hd  = rem >> 8;
  const int o   = rem & 255;
  const int h = hd >> 5, d = hd & 31;
  const float* mk = memkv + hd*NMEM;                       // mem_kv[0][h][d][j]
  float me[4];
  float z = zacc[b*NHID + hd];
  #pragma unroll
  for (int j = 0; j < 4; ++j){ me[j] = __expf(mk[j]); z += me[j]; }
  const float invz = 1.0f / z;
  const float* cp = ctxu + (size_t)((b*NH + h)*ND + d)*ND;
  const float* wp = wout + (size_t)o*NHID + h*ND;
  const float* mv = memkv + (size_t)(NHID + h*ND)*NMEM;    // mem_kv[1][h][e][j]
  float acc = 0.f;
  #pragma unroll
  for (int e = 0; e < ND; ++e){
    float ce = cp[e];
    #pragma unroll
    for (int j = 0; j < 4; ++j) ce += me[j]*mv[e*NMEM + j];
    acc += ce*wp[e];
  }
  weff[idx] = acc*invz;
}

// ---------------- K5: q-softmax(d)*SCALE -> y = Weff@qs + bias -> RMSNorm -> d_out (fp32)
// Reads q from dout rows [0:128) of its px columns (into LDS), then overwrites
// rows [0:256) of the same columns. No cross-block overlap.
__launch_bounds__(256)
__global__ void k5_out(float* dout, const float* __restrict__ weff,
                       const float* __restrict__ bout, const float* __restrict__ gout){
  __shared__ float qs[NHID][64];   // 32 KB
  __shared__ float As[16][NC];     // 16 KB
  const int t  = threadIdx.x;
  const int b  = blockIdx.y;
  const int pb = blockIdx.x * 64;
  {
    const int px = t & 63, hd0 = (t >> 6) * 32;
    const float* qp = dout + (size_t)b*NC*NPIX + pb + px;
    #pragma unroll 8
    for (int r = 0; r < 32; ++r)
      qs[hd0 + r][px] = qp[(size_t)(hd0 + r)*NPIX];
  }
  __syncthreads();
  {
    const int h = t >> 6, px = t & 63;
    float v[32]; float mx = -1e30f;
    #pragma unroll
    for (int d = 0; d < 32; ++d){ v[d] = qs[h*32 + d][px]; mx = fmaxf(mx, v[d]); }
    float se = 0.f;
    #pragma unroll
    for (int d = 0; d < 32; ++d){ v[d] = __expf(v[d] - mx); se += v[d]; }
    const float inv = QSCALE / se;
    #pragma unroll
    for (int d = 0; d < 32; ++d) qs[h*32 + d][px] = v[d]*inv;
  }
  const int tx = t & 15, ty = t >> 4;   // px tile tx*4, o tile ty*16
  float acc[16][4] = {};
  const float* wb = weff + (size_t)b*NHID*NC;
  for (int k0 = 0; k0 < NHID; k0 += 16){
    __syncthreads();
    {
      const int cc = t >> 4, ol = (t & 15)*4;
      const float* wp = wb + (size_t)(k0 + cc)*NC + ol;
      #pragma unroll
      for (int j = 0; j < 4; ++j)
        *(floatx4*)&As[cc][ol + 64*j] = *(const floatx4*)(wp + 64*j);
    }
    __syncthreads();
    #pragma unroll
    for (int kk = 0; kk < 16; ++kk){
      float a[16], bb[4];
      *(floatx4*)&bb[0] = *(const floatx4*)&qs[k0 + kk][tx*4];
      #pragma unroll
      for (int i = 0; i < 4; ++i)
        *(floatx4*)&a[4*i] = *(const floatx4*)&As[kk][ty*16 + 4*i];
      #pragma unroll
      for (int i = 0; i < 16; ++i)
        #pragma unroll
        for (int j = 0; j < 4; ++j)
          acc[i][j] += a[i]*bb[j];
    }
  }
  float ps[4] = {0.f, 0.f, 0.f, 0.f};
  #pragma unroll
  for (int i = 0; i < 16; ++i){
    const float bias = bout[ty*16 + i];
    #pragma unroll
    for (int j = 0; j < 4; ++j){ acc[i][j] += bias; ps[j] += acc[i][j]*acc[i][j]; }
  }
  __syncthreads();                 // done with qs/As -> alias for reduction
  float* red = &qs[0][0];          // 1024 floats
  float* nfp = red + 1024;         // 64 floats
  #pragma unroll
  for (int j = 0; j < 4; ++j) red[t*4 + j] = ps[j];
  __syncthreads();
  if (t < 64){
    const int txr = t >> 2, j = t & 3;
    float sum = 0.f;
    #pragma unroll
    for (int y = 0; y < 16; ++y) sum += red[(y*16 + txr)*4 + j];
    nfp[txr*4 + j] = 16.0f / fmaxf(sqrtf(sum), 1e-12f);
  }
  __syncthreads();
  float nfv[4];
  #pragma unroll
  for (int j = 0; j < 4; ++j) nfv[j] = nfp[tx*4 + j];
  float* ob = dout + (size_t)b*NC*NPIX + pb + tx*4;
  #pragma unroll
  for (int i = 0; i < 16; ++i){
    const int o = ty*16 + i;
    const float gg = gout[o];
    floatx4 ov;
    #pragma unroll
    for (int j = 0; j < 4; ++j) ov[j] = acc[i][j]*nfv[j]*gg;
    *(floatx4*)(ob + (size_t)o*NPIX) = ov;
  }
}

extern "C" void kernel_launch(void* const* d_in, const int* in_sizes, int n_in,
                              void* d_out, int out_size, void* d_ws, size_t ws_size,
                              hipStream_t stream) {
  (void)in_sizes; (void)n_in; (void)out_size; (void)ws_size;
  const float* x     = (const float*)d_in[0];
  const float* ng    = (const float*)d_in[1];
  const float* wqkv  = (const float*)d_in[2];
  const float* memkv = (const float*)d_in[3];
  const float* wout  = (const float*)d_in[4];
  const float* bout  = (const float*)d_in[5];
  const float* gout  = (const float*)d_in[6];
  float* dout = (float*)d_out;
  char* ws = (char*)d_ws;
  // workspace layout — total 2,629,632 B (~2.51 MB)
  float* s    = (float*)(ws);             // 16*4096*4        = 262144
  float* ctxu = (float*)(ws + 262144);    // 16*4*32*32*4     = 262144
  float* zacc = (float*)(ws + 524288);    // 16*128*4         = 8192
  float* weff = (float*)(ws + 532480);    // 16*128*256*4     = 2097152

  k0_zero<<<dim3(264),        256, 0, stream>>>(ctxu, 65536 + 2048);
  k1_norm<<<dim3(64, 16),     256, 0, stream>>>(x, s);
  k2_qv  <<<dim3(32, 2, 16),  256, 0, stream>>>(x, wqkv, ng, s, dout);
  k3_ctx <<<dim3(4, 8, 16),   256, 0, stream>>>(x, wqkv, ng, s, dout, ctxu, zacc);
  k4_weff<<<dim3(2048),       256, 0, stream>>>(ctxu, zacc, memkv, wout, weff);
  k5_out <<<dim3(64, 16),     256, 0, stream>>>(dout, weff, bout, gout);
}

// Round 5
// 337.236 us; speedup vs baseline: 1.2171x; 1.2171x over previous
//
#include <hip/hip_runtime.h>
#include <hip/hip_bf16.h>

typedef __hip_bfloat16 bf16;
typedef __attribute__((ext_vector_type(8))) short bf16x8;
typedef __attribute__((ext_vector_type(4))) float floatx4;

#define NB 16
#define NC 256
#define NPIX 4096
#define NHID 128
#define NH 4
#define ND 32
#define NMEM 4
#define QSCALE 0.17677669529663687f  // 32^-0.5

__device__ __forceinline__ float b2f(bf16 v){ return __bfloat162float(v); }

// ---------------- K0: zero the atomic accumulators (ctxu + zacc, contiguous)
__global__ void k0_zero(float* __restrict__ p, int n){
  int i = blockIdx.x*256 + threadIdx.x;
  if (i < n) p[i] = 0.f;
}

// ---------------- K1: per-pixel channel norm scale: s = 16 / max(||x_c||, 1e-12)
__launch_bounds__(256)
__global__ void k1_norm(const float* __restrict__ x, float* __restrict__ s){
  __shared__ float sm[4][64];
  const int t  = threadIdx.x;
  const int px = blockIdx.x * 64 + (t & 63);
  const int cg = t >> 6;
  const int b  = blockIdx.y;
  const float* xp = x + (size_t)b*NC*NPIX + (size_t)cg*64*NPIX + px;
  float acc = 0.f;
  #pragma unroll 8
  for (int c = 0; c < 64; ++c){ float v = xp[(size_t)c*NPIX]; acc += v*v; }
  sm[cg][t & 63] = acc;
  __syncthreads();
  if (cg == 0){
    float tot = sm[0][t] + sm[1][t] + sm[2][t] + sm[3][t];
    s[b*NPIX + px] = 16.0f / fmaxf(sqrtf(tot), 1e-12f);
  }
}

// ---------------- K2: fused q+v MFMA GEMM. One 64-px tile per block, 256 output
// rows (q = wqkv[0:128], v = wqkv[256:384]); x read ONCE. dout rows [0:256) fp32.
__launch_bounds__(256)
__global__ void k2_qv(const float* __restrict__ x, const float* __restrict__ wqkv,
                      const float* __restrict__ g, const float* __restrict__ s,
                      float* __restrict__ dout){
  __shared__ bf16 Ab[256][40];   // [row][k], 20.5 KB
  __shared__ bf16 Xb[64][40];    // [px][k], 5.1 KB
  const int t  = threadIdx.x;
  const int b  = blockIdx.y;
  const int pb = blockIdx.x * 64;
  const int wv = t >> 6, lane = t & 63, m = lane & 15, q4 = lane >> 4;
  const int px_st = t & 63, cg_st = t >> 6;      // X staging coords
  const int wr = (t < 128) ? t : (t + 128);      // W row for dout row t
  const float* xb = x + (size_t)b*NC*NPIX;
  floatx4 acc[4][4] = {};
  for (int k0 = 0; k0 < NC; k0 += 32){
    {  // stage A: thread t -> row t, k in [k0, k0+32)
      const float* wp = wqkv + (size_t)wr*NC + k0;
      alignas(16) bf16 tmp[32];
      #pragma unroll
      for (int q = 0; q < 8; ++q){
        floatx4 w4 = *(const floatx4*)(wp + 4*q);
        floatx4 g4 = *(const floatx4*)(g + k0 + 4*q);
        #pragma unroll
        for (int i = 0; i < 4; ++i) tmp[4*q+i] = __float2bfloat16(w4[i]*g4[i]);
      }
      #pragma unroll
      for (int q = 0; q < 4; ++q)
        *(uint4*)&Ab[t][8*q] = *(const uint4*)&tmp[8*q];
    }
    {  // stage X: px = t&63, c = k0 + cg*8 + j  -> Xb[px][k] (transposed)
      const float* xp = xb + (size_t)(k0 + cg_st*8)*NPIX + pb + px_st;
      alignas(16) bf16 tmp[8];
      #pragma unroll
      for (int j = 0; j < 8; ++j) tmp[j] = __float2bfloat16(xp[(size_t)j*NPIX]);
      *(uint4*)&Xb[px_st][cg_st*8] = *(const uint4*)tmp;
    }
    __syncthreads();
    bf16x8 bfr[4];
    #pragma unroll
    for (int pt = 0; pt < 4; ++pt)
      bfr[pt] = *(const bf16x8*)&Xb[pt*16 + m][q4*8];
    #pragma unroll
    for (int rt = 0; rt < 4; ++rt){
      bf16x8 af = *(const bf16x8*)&Ab[wv*64 + rt*16 + m][q4*8];
      #pragma unroll
      for (int pt = 0; pt < 4; ++pt)
        acc[rt][pt] = __builtin_amdgcn_mfma_f32_16x16x32_bf16(af, bfr[pt], acc[rt][pt], 0, 0, 0);
    }
    __syncthreads();
  }
  float sv[4];
  #pragma unroll
  for (int pt = 0; pt < 4; ++pt) sv[pt] = s[b*NPIX + pb + pt*16 + m];
  #pragma unroll
  for (int rt = 0; rt < 4; ++rt){
    const int row = wv*64 + rt*16 + q4*4;   // C/D: col=lane&15(px), row=q4*4+r
    float* op = dout + (size_t)(b*NC + row)*NPIX + pb + m;
    #pragma unroll
    for (int pt = 0; pt < 4; ++pt)
      #pragma unroll
      for (int r = 0; r < 4; ++r)
        op[(size_t)r*NPIX + pt*16] = acc[rt][pt][r]*sv[pt];
  }
}

// ---------------- K3: MFMA k-scores + exp + ctx/z accumulation.
// Block (h, pxb, b): 128-px tile; wave wv owns px sub-tile wv*32.
__launch_bounds__(256)
__global__ void k3_ctx(const float* __restrict__ x, const float* __restrict__ wqkv,
                       const float* __restrict__ g, const float* __restrict__ s,
                       const float* __restrict__ dout,
                       float* __restrict__ ctxu, float* __restrict__ zacc){
  __shared__ bf16 Ak[32][264];   // wk*g, full K resident, 16.9 KB
  __shared__ bf16 Xb[128][40];   // [px][k] per K-step, 10.25 KB
  __shared__ bf16 Pb[32][136];   // P tile [d][px], 8.7 KB
  const int t = threadIdx.x;
  const int h = blockIdx.x, pxb = blockIdx.y, b = blockIdx.z;
  const int wv = t >> 6, lane = t & 63, m = lane & 15, q4 = lane >> 4;
  const int px0 = pxb * 128;
  {  // stage Ak once: d = t>>3, 32 k's from (t&7)*32
    const int d = t >> 3, ks = (t & 7)*32;
    const float* wp = wqkv + (size_t)(NHID + h*ND + d)*NC + ks;
    alignas(16) bf16 tmp[32];
    #pragma unroll
    for (int q = 0; q < 8; ++q){
      floatx4 w4 = *(const floatx4*)(wp + 4*q);
      floatx4 g4 = *(const floatx4*)(g + ks + 4*q);
      #pragma unroll
      for (int i = 0; i < 4; ++i) tmp[4*q+i] = __float2bfloat16(w4[i]*g4[i]);
    }
    #pragma unroll
    for (int q = 0; q < 4; ++q)
      *(uint4*)&Ak[d][ks + 8*q] = *(const uint4*)&tmp[8*q];
  }
  const float* xb = x + (size_t)b*NC*NPIX;
  floatx4 kacc[2][2] = {};
  for (int k0 = 0; k0 < NC; k0 += 32){
    __syncthreads();   // Ak ready (iter 0) / previous MFMA reads of Xb done
    {  // stage X: px = t&127, c = k0 + cg*16 + j -> Xb[px][k]
      const int px = t & 127, cg = t >> 7;
      const float* xp = xb + (size_t)(k0 + cg*16)*NPIX + px0 + px;
      alignas(16) bf16 tmp[16];
      #pragma unroll
      for (int j = 0; j < 16; ++j) tmp[j] = __float2bfloat16(xp[(size_t)j*NPIX]);
      *(uint4*)&Xb[px][cg*16]     = *(const uint4*)&tmp[0];
      *(uint4*)&Xb[px][cg*16 + 8] = *(const uint4*)&tmp[8];
    }
    __syncthreads();
    bf16x8 bfr[2];
    #pragma unroll
    for (int pt = 0; pt < 2; ++pt)
      bfr[pt] = *(const bf16x8*)&Xb[wv*32 + pt*16 + m][q4*8];
    #pragma unroll
    for (int dt = 0; dt < 2; ++dt){
      bf16x8 af = *(const bf16x8*)&Ak[dt*16 + m][k0 + q4*8];
      #pragma unroll
      for (int pt = 0; pt < 2; ++pt)
        kacc[dt][pt] = __builtin_amdgcn_mfma_f32_16x16x32_bf16(af, bfr[pt], kacc[dt][pt], 0, 0, 0);
    }
  }
  // exp + P-store + z partials (no sync needed: Pb disjoint from Xb/Ak)
  float zreg[2][4] = {};
  #pragma unroll
  for (int pt = 0; pt < 2; ++pt){
    const int pxl = wv*32 + pt*16 + m;
    const float sv = s[b*NPIX + px0 + pxl];
    #pragma unroll
    for (int dt = 0; dt < 2; ++dt)
      #pragma unroll
      for (int r = 0; r < 4; ++r){
        float p = __expf(kacc[dt][pt][r]*sv);
        zreg[dt][r] += p;
        Pb[dt*16 + q4*4 + r][pxl] = __float2bfloat16(p);
      }
  }
  __syncthreads();
  // ctx MFMA: wave's toks = wv*32..+32 (K=32 in one 16x16x32 frag)
  const float* vb = dout + (size_t)(b*NC + NHID + h*ND)*NPIX + px0 + wv*32;
  floatx4 ctx[2][2] = {};
  #pragma unroll
  for (int et = 0; et < 2; ++et){
    const float* vp = vb + (size_t)(et*16 + m)*NPIX + q4*8;
    floatx4 v0 = *(const floatx4*)vp;
    floatx4 v1 = *(const floatx4*)(vp + 4);
    alignas(16) bf16 vt[8];
    #pragma unroll
    for (int i = 0; i < 4; ++i){ vt[i] = __float2bfloat16(v0[i]); vt[4+i] = __float2bfloat16(v1[i]); }
    bf16x8 vf = *(const bf16x8*)vt;
    #pragma unroll
    for (int dt = 0; dt < 2; ++dt){
      bf16x8 pf = *(const bf16x8*)&Pb[dt*16 + m][wv*32 + q4*8];
      ctx[dt][et] = __builtin_amdgcn_mfma_f32_16x16x32_bf16(pf, vf, ctx[dt][et], 0, 0, 0);
    }
  }
  // z: reduce over the 16 lanes (m) holding the same d, then atomics
  #pragma unroll
  for (int dt = 0; dt < 2; ++dt)
    #pragma unroll
    for (int r = 0; r < 4; ++r){
      float v = zreg[dt][r];
      #pragma unroll
      for (int off = 8; off > 0; off >>= 1) v += __shfl_xor(v, off, 64);
      if (m == 0) atomicAdd(&zacc[b*NHID + h*ND + dt*16 + q4*4 + r], v);
    }
  // ctx: C/D col = e = lane&15, row d = q4*4 + r
  float* cb = ctxu + (size_t)(b*NH + h)*ND*ND;
  #pragma unroll
  for (int dt = 0; dt < 2; ++dt)
    #pragma unroll
    for (int et = 0; et < 2; ++et)
      #pragma unroll
      for (int r = 0; r < 4; ++r)
        atomicAdd(&cb[(dt*16 + q4*4 + r)*ND + et*16 + m], ctx[dt][et][r]);
}

// ---------------- K4: Weff[b][hd][o] = sum_e wout[o][h*32+e]*ctx_final[b][h][d][e]
// ctx_final = (ctxu + sum_j exp(mk[d][j])*mv[e][j]) / (z[d] + sum_j exp(mk[d][j]))
__launch_bounds__(256)
__global__ void k4_weff(const float* __restrict__ ctxu, const float* __restrict__ zacc,
                        const float* __restrict__ memkv, const float* __restrict__ wout,
                        float* __restrict__ weff){
  const int idx = blockIdx.x*256 + threadIdx.x;   // (b*128+hd)*256 + o
  const int b   = idx >> 15;
  const int rem = idx & 32767;
  const int hd  = rem >> 8;
  const int o   = rem & 255;
  const int h = hd >> 5, d = hd & 31;
  const float* mk = memkv + hd*NMEM;                       // mem_kv[0][h][d][j]
  float me[4];
  float z = zacc[b*NHID + hd];
  #pragma unroll
  for (int j = 0; j < 4; ++j){ me[j] = __expf(mk[j]); z += me[j]; }
  const float invz = 1.0f / z;
  const float* cp = ctxu + (size_t)((b*NH + h)*ND + d)*ND;
  const float* wp = wout + (size_t)o*NHID + h*ND;
  const float* mv = memkv + (size_t)(NHID + h*ND)*NMEM;    // mem_kv[1][h][e][j]
  float acc = 0.f;
  #pragma unroll
  for (int e = 0; e < ND; ++e){
    float ce = cp[e];
    #pragma unroll
    for (int j = 0; j < 4; ++j) ce += me[j]*mv[e*NMEM + j];
    acc += ce*wp[e];
  }
  weff[idx] = acc*invz;
}

// ---------------- K5: q-softmax(d)*SCALE -> y = Weff@qs + bias -> RMSNorm -> d_out (fp32)
// Reads q from dout rows [0:128) of its px columns (into LDS), then overwrites
// rows [0:256) of the same columns. No cross-block overlap.
__launch_bounds__(256)
__global__ void k5_out(float* dout, const float* __restrict__ weff,
                       const float* __restrict__ bout, const float* __restrict__ gout){
  __shared__ float qs[NHID][64];   // 32 KB
  __shared__ float As[16][NC];     // 16 KB
  const int t  = threadIdx.x;
  const int b  = blockIdx.y;
  const int pb = blockIdx.x * 64;
  {
    const int px = t & 63, hd0 = (t >> 6) * 32;
    const float* qp = dout + (size_t)b*NC*NPIX + pb + px;
    #pragma unroll 8
    for (int r = 0; r < 32; ++r)
      qs[hd0 + r][px] = qp[(size_t)(hd0 + r)*NPIX];
  }
  __syncthreads();
  {
    const int h = t >> 6, px = t & 63;
    float v[32]; float mx = -1e30f;
    #pragma unroll
    for (int d = 0; d < 32; ++d){ v[d] = qs[h*32 + d][px]; mx = fmaxf(mx, v[d]); }
    float se = 0.f;
    #pragma unroll
    for (int d = 0; d < 32; ++d){ v[d] = __expf(v[d] - mx); se += v[d]; }
    const float inv = QSCALE / se;
    #pragma unroll
    for (int d = 0; d < 32; ++d) qs[h*32 + d][px] = v[d]*inv;
  }
  const int tx = t & 15, ty = t >> 4;   // px tile tx*4, o tile ty*16
  float acc[16][4] = {};
  const float* wb = weff + (size_t)b*NHID*NC;
  for (int k0 = 0; k0 < NHID; k0 += 16){
    __syncthreads();
    {
      const int cc = t >> 4, ol = (t & 15)*4;
      const float* wp = wb + (size_t)(k0 + cc)*NC + ol;
      #pragma unroll
      for (int j = 0; j < 4; ++j)
        *(floatx4*)&As[cc][ol + 64*j] = *(const floatx4*)(wp + 64*j);
    }
    __syncthreads();
    #pragma unroll
    for (int kk = 0; kk < 16; ++kk){
      float a[16], bb[4];
      *(floatx4*)&bb[0] = *(const floatx4*)&qs[k0 + kk][tx*4];
      #pragma unroll
      for (int i = 0; i < 4; ++i)
        *(floatx4*)&a[4*i] = *(const floatx4*)&As[kk][ty*16 + 4*i];
      #pragma unroll
      for (int i = 0; i < 16; ++i)
        #pragma unroll
        for (int j = 0; j < 4; ++j)
          acc[i][j] += a[i]*bb[j];
    }
  }
  float ps[4] = {0.f, 0.f, 0.f, 0.f};
  #pragma unroll
  for (int i = 0; i < 16; ++i){
    const float bias = bout[ty*16 + i];
    #pragma unroll
    for (int j = 0; j < 4; ++j){ acc[i][j] += bias; ps[j] += acc[i][j]*acc[i][j]; }
  }
  __syncthreads();                 // done with qs/As -> alias for reduction
  float* red = &qs[0][0];          // 1024 floats
  float* nfp = red + 1024;         // 64 floats
  #pragma unroll
  for (int j = 0; j < 4; ++j) red[t*4 + j] = ps[j];
  __syncthreads();
  if (t < 64){
    const int txr = t >> 2, j = t & 3;
    float sum = 0.f;
    #pragma unroll
    for (int y = 0; y < 16; ++y) sum += red[(y*16 + txr)*4 + j];
    nfp[txr*4 + j] = 16.0f / fmaxf(sqrtf(sum), 1e-12f);
  }
  __syncthreads();
  float nfv[4];
  #pragma unroll
  for (int j = 0; j < 4; ++j) nfv[j] = nfp[tx*4 + j];
  float* ob = dout + (size_t)b*NC*NPIX + pb + tx*4;
  #pragma unroll
  for (int i = 0; i < 16; ++i){
    const int o = ty*16 + i;
    const float gg = gout[o];
    floatx4 ov;
    #pragma unroll
    for (int j = 0; j < 4; ++j) ov[j] = acc[i][j]*nfv[j]*gg;
    *(floatx4*)(ob + (size_t)o*NPIX) = ov;
  }
}

extern "C" void kernel_launch(void* const* d_in, const int* in_sizes, int n_in,
                              void* d_out, int out_size, void* d_ws, size_t ws_size,
                              hipStream_t stream) {
  (void)in_sizes; (void)n_in; (void)out_size; (void)ws_size;
  const float* x     = (const float*)d_in[0];
  const float* ng    = (const float*)d_in[1];
  const float* wqkv  = (const float*)d_in[2];
  const float* memkv = (const float*)d_in[3];
  const float* wout  = (const float*)d_in[4];
  const float* bout  = (const float*)d_in[5];
  const float* gout  = (const float*)d_in[6];
  float* dout = (float*)d_out;
  char* ws = (char*)d_ws;
  // workspace layout — total 2,629,632 B (~2.51 MB)
  float* s    = (float*)(ws);             // 16*4096*4        = 262144
  float* ctxu = (float*)(ws + 262144);    // 16*4*32*32*4     = 262144
  float* zacc = (float*)(ws + 524288);    // 16*128*4         = 8192
  float* weff = (float*)(ws + 532480);    // 16*128*256*4     = 2097152

  k0_zero<<<dim3(264),        256, 0, stream>>>(ctxu, 65536 + 2048);
  k1_norm<<<dim3(64, 16),     256, 0, stream>>>(x, s);
  k2_qv  <<<dim3(64, 16),     256, 0, stream>>>(x, wqkv, ng, s, dout);
  k3_ctx <<<dim3(4, 32, 16),  256, 0, stream>>>(x, wqkv, ng, s, dout, ctxu, zacc);
  k4_weff<<<dim3(2048),       256, 0, stream>>>(ctxu, zacc, memkv, wout, weff);
  k5_out <<<dim3(64, 16),     256, 0, stream>>>(dout, weff, bout, gout);
}

// Round 6
// 233.508 us; speedup vs baseline: 1.7578x; 1.4442x over previous
//
#include <hip/hip_runtime.h>
#include <hip/hip_bf16.h>

typedef __hip_bfloat16 bf16;
typedef __attribute__((ext_vector_type(8))) short bf16x8;
typedef __attribute__((ext_vector_type(4))) float floatx4;

#define NB 16
#define NC 256
#define NPIX 4096
#define NHID 128
#define NH 4
#define ND 32
#define NMEM 4
#define QSCALE 0.17677669529663687f  // 32^-0.5

// ---------------- K0: zero the atomic accumulators (ctxu + zacc, contiguous)
__global__ void k0_zero(float* __restrict__ p, int n){
  int i = blockIdx.x*256 + threadIdx.x;
  if (i < n) p[i] = 0.f;
}

__device__ __forceinline__ void stage_wrow(bf16* dst, const float* wp, const float* gp){
  alignas(16) bf16 tmp[32];
  #pragma unroll
  for (int q = 0; q < 8; ++q){
    floatx4 w4 = *(const floatx4*)(wp + 4*q);
    floatx4 g4 = *(const floatx4*)(gp + 4*q);
    #pragma unroll
    for (int i = 0; i < 4; ++i) tmp[4*q+i] = __float2bfloat16(w4[i]*g4[i]);
  }
  #pragma unroll
  for (int q = 0; q < 4; ++q) *(uint4*)(dst + 8*q) = *(const uint4*)&tmp[8*q];
}

// ---------------- kA: fused norm + qkv GEMM + q-softmax + P/ctx/z.
// Block = (64-px tile, batch). Computes all 384 wqkv rows via MFMA from one
// LDS x tile; s from the same loads. q (rows 0..127, softmaxed*SCALE) -> dout.
// k -> P=exp(k*s) -> LDS; v -> LDS; per-head ctx MFMA -> atomics. v/k never
// touch global.
__launch_bounds__(256)
__global__ void kA(const float* __restrict__ x, const float* __restrict__ wqkv,
                   const float* __restrict__ g, float* __restrict__ dout,
                   float* __restrict__ ctxu, float* __restrict__ zacc){
  __shared__ char smem alignas(16) [38144];
  bf16 (*Ab)[40] = (bf16(*)[40])smem;             // [384][40] = 30720 B (GEMM phase)
  bf16 (*Xb)[40] = (bf16(*)[40])(smem + 30720);   // [64][40]  = 5120 B  (GEMM phase)
  bf16 (*Pb)[72] = (bf16(*)[72])smem;             // [128][72] = 18432 B (post, alias)
  bf16 (*Vb)[72] = (bf16(*)[72])(smem + 18432);   // [128][72] = 18432 B (post, alias)
  float* ssqL = (float*)(smem + 36864);           // [4][64] — disjoint from all above
  float* sL   = (float*)(smem + 37888);           // [64]
  const int t = threadIdx.x;
  const int pb = blockIdx.x * 64, b = blockIdx.y;
  const int wv = t >> 6, lane = t & 63, m = lane & 15, q4 = lane >> 4;
  const int px_st = t & 63, cg_st = t >> 6;
  const float* xb = x + (size_t)b*NC*NPIX;
  float ssq = 0.f;
  floatx4 acc[6][4] = {};
  for (int k0 = 0; k0 < NC; k0 += 32){
    __syncthreads();   // protect Ab/Xb from previous step's MFMA readers
    stage_wrow(&Ab[t][0], wqkv + (size_t)t*NC + k0, g + k0);
    if (t < 128) stage_wrow(&Ab[256 + t][0], wqkv + (size_t)(256 + t)*NC + k0, g + k0);
    {  // stage x^T chunk + ssq partials
      const float* xp = xb + (size_t)(k0 + cg_st*8)*NPIX + pb + px_st;
      alignas(16) bf16 tmp[8];
      #pragma unroll
      for (int j = 0; j < 8; ++j){
        float v = xp[(size_t)j*NPIX];
        ssq += v*v;
        tmp[j] = __float2bfloat16(v);
      }
      *(uint4*)&Xb[px_st][cg_st*8] = *(const uint4*)tmp;
    }
    __syncthreads();
    bf16x8 bfr[4];
    #pragma unroll
    for (int pt = 0; pt < 4; ++pt)
      bfr[pt] = *(const bf16x8*)&Xb[pt*16 + m][q4*8];
    #pragma unroll
    for (int rt = 0; rt < 6; ++rt){
      bf16x8 af = *(const bf16x8*)&Ab[wv*96 + rt*16 + m][q4*8];
      #pragma unroll
      for (int pt = 0; pt < 4; ++pt)
        acc[rt][pt] = __builtin_amdgcn_mfma_f32_16x16x32_bf16(af, bfr[pt], acc[rt][pt], 0, 0, 0);
    }
  }
  // finalize s (per px)
  ssqL[cg_st*64 + px_st] = ssq;
  __syncthreads();
  if (t < 64){
    float tot = ssqL[t] + ssqL[64 + t] + ssqL[128 + t] + ssqL[192 + t];
    sL[t] = 16.0f / fmaxf(sqrtf(tot), 1e-12f);
  }
  __syncthreads();   // sL ready; all MFMA reads of Ab/Xb done -> Pb/Vb writable
  float sv[4];
  #pragma unroll
  for (int pt = 0; pt < 4; ++pt) sv[pt] = sL[pt*16 + m];
  #pragma unroll
  for (int pr = 0; pr < 3; ++pr){
    const int ra = 2*pr, rb = 2*pr + 1;
    const int row0 = wv*96 + pr*32;
    const int type = row0 >> 7;          // 0=q, 1=k, 2=v (uniform per 32-row pair)
    if (type == 0){
      // q: softmax over the head's 32 rows (2 tiles x 4 r in-lane, q4 via shuffle)
      #pragma unroll
      for (int pt = 0; pt < 4; ++pt){
        float va[4], vb[4];
        float mx = -1e30f;
        #pragma unroll
        for (int r = 0; r < 4; ++r){
          va[r] = acc[ra][pt][r]*sv[pt];
          vb[r] = acc[rb][pt][r]*sv[pt];
          mx = fmaxf(mx, fmaxf(va[r], vb[r]));
        }
        mx = fmaxf(mx, __shfl_xor(mx, 16, 64));
        mx = fmaxf(mx, __shfl_xor(mx, 32, 64));
        float se = 0.f;
        #pragma unroll
        for (int r = 0; r < 4; ++r){
          va[r] = __expf(va[r] - mx); vb[r] = __expf(vb[r] - mx);
          se += va[r] + vb[r];
        }
        se += __shfl_xor(se, 16, 64);
        se += __shfl_xor(se, 32, 64);
        const float inv = QSCALE / se;
        float* op = dout + (size_t)(b*NC + row0 + q4*4)*NPIX + pb + pt*16 + m;
        #pragma unroll
        for (int r = 0; r < 4; ++r){
          op[(size_t)r*NPIX] = va[r]*inv;
          op[(size_t)(16 + r)*NPIX] = vb[r]*inv;
        }
      }
    } else if (type == 1){
      const int d0 = row0 - 128;
      float za[4] = {}, zb[4] = {};
      #pragma unroll
      for (int pt = 0; pt < 4; ++pt){
        #pragma unroll
        for (int r = 0; r < 4; ++r){
          float pa = __expf(acc[ra][pt][r]*sv[pt]);
          float pv = __expf(acc[rb][pt][r]*sv[pt]);
          za[r] += pa; zb[r] += pv;
          Pb[d0      + q4*4 + r][pt*16 + m] = __float2bfloat16(pa);
          Pb[d0 + 16 + q4*4 + r][pt*16 + m] = __float2bfloat16(pv);
        }
      }
      #pragma unroll
      for (int r = 0; r < 4; ++r){
        #pragma unroll
        for (int o = 1; o < 16; o <<= 1){
          za[r] += __shfl_xor(za[r], o, 64);
          zb[r] += __shfl_xor(zb[r], o, 64);
        }
      }
      if (m == 0){
        #pragma unroll
        for (int r = 0; r < 4; ++r){
          atomicAdd(&zacc[b*NHID + d0      + q4*4 + r], za[r]);
          atomicAdd(&zacc[b*NHID + d0 + 16 + q4*4 + r], zb[r]);
        }
      }
    } else {
      const int v0 = row0 - 256;
      #pragma unroll
      for (int pt = 0; pt < 4; ++pt)
        #pragma unroll
        for (int r = 0; r < 4; ++r){
          Vb[v0      + q4*4 + r][pt*16 + m] = __float2bfloat16(acc[ra][pt][r]*sv[pt]);
          Vb[v0 + 16 + q4*4 + r][pt*16 + m] = __float2bfloat16(acc[rb][pt][r]*sv[pt]);
        }
    }
  }
  __syncthreads();
  // ctx MFMA: wave wv = head wv; toks = 64 px in 2 K-steps
  floatx4 cx[2][2] = {};
  #pragma unroll
  for (int k0t = 0; k0t < 64; k0t += 32){
    bf16x8 af[2], bf[2];
    #pragma unroll
    for (int dt = 0; dt < 2; ++dt) af[dt] = *(const bf16x8*)&Pb[wv*32 + dt*16 + m][k0t + q4*8];
    #pragma unroll
    for (int et = 0; et < 2; ++et) bf[et] = *(const bf16x8*)&Vb[wv*32 + et*16 + m][k0t + q4*8];
    #pragma unroll
    for (int dt = 0; dt < 2; ++dt)
      #pragma unroll
      for (int et = 0; et < 2; ++et)
        cx[dt][et] = __builtin_amdgcn_mfma_f32_16x16x32_bf16(af[dt], bf[et], cx[dt][et], 0, 0, 0);
  }
  float* cb = ctxu + (size_t)(b*NH + wv)*ND*ND;
  #pragma unroll
  for (int dt = 0; dt < 2; ++dt)
    #pragma unroll
    for (int et = 0; et < 2; ++et)
      #pragma unroll
      for (int r = 0; r < 4; ++r)
        atomicAdd(&cb[(dt*16 + q4*4 + r)*ND + et*16 + m], cx[dt][et][r]);
}

// ---------------- K4: WeffT[b][o][hd] = (1/z[hd]) * sum_e wout[o][h*32+e]*ctx_f[d][e]
__launch_bounds__(256)
__global__ void k4_weff(const float* __restrict__ ctxu, const float* __restrict__ zacc,
                        const float* __restrict__ memkv, const float* __restrict__ wout,
                        float* __restrict__ weffT){
  const int idx = blockIdx.x*256 + threadIdx.x;   // (b*256 + o)*128 + hd
  const int b   = idx >> 15;
  const int o   = (idx >> 7) & 255;
  const int hd  = idx & 127;
  const int h = hd >> 5, d = hd & 31;
  const float* mk = memkv + hd*NMEM;                       // mem_kv[0][h][d][j]
  float me[4];
  float z = zacc[b*NHID + hd];
  #pragma unroll
  for (int j = 0; j < 4; ++j){ me[j] = __expf(mk[j]); z += me[j]; }
  const float invz = 1.0f / z;
  const float* cp = ctxu + (size_t)((b*NH + h)*ND + d)*ND;
  const float* wp = wout + (size_t)o*NHID + h*ND;
  const float* mv = memkv + (size_t)(NHID + h*ND)*NMEM;    // mem_kv[1][h][e][j]
  float acc = 0.f;
  #pragma unroll
  for (int e = 0; e < ND; ++e){
    float ce = cp[e];
    #pragma unroll
    for (int j = 0; j < 4; ++j) ce += me[j]*mv[e*NMEM + j];
    acc += ce*wp[e];
  }
  weffT[idx] = acc*invz;
}

// ---------------- K5: MFMA y = WeffT @ q_s + bias -> RMSNorm -> d_out rows 0..255.
// Reads q_s (rows 0..127 of its px cols, staged per K-step) before any write.
__launch_bounds__(256)
__global__ void k5_out(float* dout, const float* __restrict__ weffT,
                       const float* __restrict__ bout, const float* __restrict__ gout){
  __shared__ bf16 Wb[256][40];   // 20480 B
  __shared__ bf16 Qb[64][40];    // 5120 B
  __shared__ float red[4][64];
  __shared__ float nf[64];
  const int t = threadIdx.x;
  const int pb = blockIdx.x * 64, b = blockIdx.y;
  const int wv = t >> 6, lane = t & 63, m = lane & 15, q4 = lane >> 4;
  const int px_st = t & 63, cg_st = t >> 6;
  floatx4 acc[4][4] = {};
  for (int k0 = 0; k0 < NHID; k0 += 32){
    __syncthreads();
    {  // stage WeffT row t (bf16)
      const float* wp = weffT + ((size_t)b*NC + t)*NHID + k0;
      alignas(16) bf16 tmp[32];
      #pragma unroll
      for (int q = 0; q < 8; ++q){
        floatx4 w4 = *(const floatx4*)(wp + 4*q);
        #pragma unroll
        for (int i = 0; i < 4; ++i) tmp[4*q+i] = __float2bfloat16(w4[i]);
      }
      #pragma unroll
      for (int q = 0; q < 4; ++q) *(uint4*)&Wb[t][8*q] = *(const uint4*)&tmp[8*q];
    }
    {  // stage q_s^T chunk
      const float* qp = dout + (size_t)(b*NC + k0 + cg_st*8)*NPIX + pb + px_st;
      alignas(16) bf16 tmp[8];
      #pragma unroll
      for (int j = 0; j < 8; ++j) tmp[j] = __float2bfloat16(qp[(size_t)j*NPIX]);
      *(uint4*)&Qb[px_st][cg_st*8] = *(const uint4*)tmp;
    }
    __syncthreads();
    bf16x8 bfr[4];
    #pragma unroll
    for (int pt = 0; pt < 4; ++pt)
      bfr[pt] = *(const bf16x8*)&Qb[pt*16 + m][q4*8];
    #pragma unroll
    for (int rt = 0; rt < 4; ++rt){
      bf16x8 af = *(const bf16x8*)&Wb[wv*64 + rt*16 + m][q4*8];
      #pragma unroll
      for (int pt = 0; pt < 4; ++pt)
        acc[rt][pt] = __builtin_amdgcn_mfma_f32_16x16x32_bf16(af, bfr[pt], acc[rt][pt], 0, 0, 0);
    }
  }
  // bias + ssq partials
  float ps[4] = {0.f, 0.f, 0.f, 0.f};
  #pragma unroll
  for (int rt = 0; rt < 4; ++rt){
    const int row = wv*64 + rt*16 + q4*4;
    #pragma unroll
    for (int r = 0; r < 4; ++r){
      const float bias = bout[row + r];
      #pragma unroll
      for (int pt = 0; pt < 4; ++pt){
        acc[rt][pt][r] += bias;
        ps[pt] += acc[rt][pt][r]*acc[rt][pt][r];
      }
    }
  }
  #pragma unroll
  for (int pt = 0; pt < 4; ++pt){
    ps[pt] += __shfl_xor(ps[pt], 16, 64);
    ps[pt] += __shfl_xor(ps[pt], 32, 64);
  }
  if (q4 == 0){
    #pragma unroll
    for (int pt = 0; pt < 4; ++pt) red[wv][pt*16 + m] = ps[pt];
  }
  __syncthreads();
  if (t < 64){
    float tot = red[0][t] + red[1][t] + red[2][t] + red[3][t];
    nf[t] = 16.0f / fmaxf(sqrtf(tot), 1e-12f);
  }
  __syncthreads();
  float nv[4];
  #pragma unroll
  for (int pt = 0; pt < 4; ++pt) nv[pt] = nf[pt*16 + m];
  #pragma unroll
  for (int rt = 0; rt < 4; ++rt){
    const int row = wv*64 + rt*16 + q4*4;
    #pragma unroll
    for (int r = 0; r < 4; ++r){
      const float gg = gout[row + r];
      float* op = dout + (size_t)(b*NC + row + r)*NPIX + pb + m;
      #pragma unroll
      for (int pt = 0; pt < 4; ++pt)
        op[pt*16] = acc[rt][pt][r]*nv[pt]*gg;
    }
  }
}

extern "C" void kernel_launch(void* const* d_in, const int* in_sizes, int n_in,
                              void* d_out, int out_size, void* d_ws, size_t ws_size,
                              hipStream_t stream) {
  (void)in_sizes; (void)n_in; (void)out_size; (void)ws_size;
  const float* x     = (const float*)d_in[0];
  const float* ng    = (const float*)d_in[1];
  const float* wqkv  = (const float*)d_in[2];
  const float* memkv = (const float*)d_in[3];
  const float* wout  = (const float*)d_in[4];
  const float* bout  = (const float*)d_in[5];
  const float* gout  = (const float*)d_in[6];
  float* dout = (float*)d_out;
  char* ws = (char*)d_ws;
  // workspace layout — total 2,367,488 B (~2.26 MB)
  float* ctxu  = (float*)(ws);             // 16*4*32*32*4 = 262144
  float* zacc  = (float*)(ws + 262144);    // 16*128*4     = 8192
  float* weffT = (float*)(ws + 270336);    // 16*256*128*4 = 2097152

  k0_zero<<<dim3(264),       256, 0, stream>>>(ctxu, 65536 + 2048);
  kA     <<<dim3(64, 16),    256, 0, stream>>>(x, wqkv, ng, dout, ctxu, zacc);
  k4_weff<<<dim3(2048),      256, 0, stream>>>(ctxu, zacc, memkv, wout, weffT);
  k5_out <<<dim3(64, 16),    256, 0, stream>>>(dout, weffT, bout, gout);
}

// Round 7
// 190.143 us; speedup vs baseline: 2.1587x; 1.2281x over previous
//
#include <hip/hip_runtime.h>
#include <hip/hip_bf16.h>

typedef __hip_bfloat16 bf16;
typedef __attribute__((ext_vector_type(8))) short bf16x8;
typedef __attribute__((ext_vector_type(4))) float floatx4;

#define NB 16
#define NC 256
#define NPIX 4096
#define NHID 128
#define NH 4
#define ND 32
#define NMEM 4
#define QSCALE 0.17677669529663687f  // 32^-0.5

__device__ __forceinline__ void dma16(const void* g, void* l){
  __builtin_amdgcn_global_load_lds(
      (const __attribute__((address_space(1))) unsigned int*)g,
      (__attribute__((address_space(3))) unsigned int*)l, 16, 0, 0);
}

// ---------------- K0: zero atomic accumulators
__global__ void k0_zero(float* __restrict__ p, int n){
  int i = blockIdx.x*256 + threadIdx.x;
  if (i < n) p[i] = 0.f;
}

// ---------------- kW: pack wqkv*g -> bf16 in MFMA A-frag tile order.
// 16B chunk u: slice s=u/1536, tile=(u%1536)>>6, lane l=u&63;
// row = tile*16 + (l&15); k = s*32 + (l>>4)*8 + j (j=0..7).
__launch_bounds__(256)
__global__ void kW(const float* __restrict__ wqkv, const float* __restrict__ g,
                   bf16* __restrict__ wgpack){
  const int u = blockIdx.x*256 + threadIdx.x;     // 12288 chunks
  const int s = u / 1536;
  const int r = u - s*1536;
  const int tile = r >> 6, l = r & 63;
  const int row = tile*16 + (l & 15);
  const int kb  = s*32 + (l >> 4)*8;
  const float* wp = wqkv + (size_t)row*NC + kb;
  floatx4 w0 = *(const floatx4*)wp;
  floatx4 w1 = *(const floatx4*)(wp + 4);
  floatx4 g0 = *(const floatx4*)(g + kb);
  floatx4 g1 = *(const floatx4*)(g + kb + 4);
  alignas(16) bf16 tmp[8];
  #pragma unroll
  for (int i = 0; i < 4; ++i){
    tmp[i]   = __float2bfloat16(w0[i]*g0[i]);
    tmp[4+i] = __float2bfloat16(w1[i]*g1[i]);
  }
  *(uint4*)(wgpack + (size_t)u*8) = *(const uint4*)tmp;
}

// ---------------- kA: fused norm + qkv GEMM (DMA-staged w) + q-softmax + P/ctx/z.
// Block = (64-px, b). q (softmaxed*SCALE, bf16, k5-frag order) -> dout rows 0..63
// of own px columns. k->P=exp, v -> LDS; per-head ctx MFMA -> atomics.
__launch_bounds__(256)
__global__ void kA(const float* __restrict__ x, const bf16* __restrict__ wgpack,
                   float* __restrict__ dout,
                   float* __restrict__ ctxu, float* __restrict__ zacc){
  __shared__ char smem alignas(16) [38144];
  bf16* Ab = (bf16*)smem;                        // 24 tiles x 1KB = 24576 (GEMM)
  bf16 (*Xb)[40] = (bf16(*)[40])(smem + 24576);  // [64][40] = 5120 (GEMM)
  bf16 (*Pb)[72] = (bf16(*)[72])smem;            // [128][72] = 18432 (post, alias)
  bf16 (*Vb)[72] = (bf16(*)[72])(smem + 18432);  // [128][72] = 18432 (post, alias)
  float* ssqL = (float*)(smem + 36864);          // [4][64]
  float* sL   = (float*)(smem + 37888);          // [64]
  const int t = threadIdx.x;
  const int pb = blockIdx.x * 64, b = blockIdx.y;
  const int wv = t >> 6, lane = t & 63, m = lane & 15, q4 = lane >> 4;
  const int px_st = t & 63, cg_st = t >> 6;
  const float* xb = x + (size_t)b*NC*NPIX;
  float ssq = 0.f;
  floatx4 acc[6][4] = {};
  for (int s = 0; s < 8; ++s){
    __syncthreads();   // prev MFMA done reading Ab/Xb
    {  // DMA w: wave wv loads its own 6 tiles (rows wv*96..+96)
      const bf16* gt = wgpack + ((size_t)(s*24 + wv*6)*64 + lane)*8;
      char* lt = smem + wv*6144;
      #pragma unroll
      for (int tt = 0; tt < 6; ++tt)
        dma16(gt + tt*512, lt + tt*1024);
    }
    {  // stage x^T chunk + ssq partials
      const float* xp = xb + (size_t)(s*32 + cg_st*8)*NPIX + pb + px_st;
      alignas(16) bf16 tmp[8];
      #pragma unroll
      for (int j = 0; j < 8; ++j){
        float v = xp[(size_t)j*NPIX];
        ssq += v*v;
        tmp[j] = __float2bfloat16(v);
      }
      *(uint4*)&Xb[px_st][cg_st*8] = *(const uint4*)tmp;
    }
    __syncthreads();   // barrier drains vmcnt(0): DMA + ds_write visible
    bf16x8 bfr[4];
    #pragma unroll
    for (int pt = 0; pt < 4; ++pt)
      bfr[pt] = *(const bf16x8*)&Xb[pt*16 + m][q4*8];
    #pragma unroll
    for (int rt = 0; rt < 6; ++rt){
      bf16x8 af = *(const bf16x8*)(Ab + (size_t)wv*3072 + rt*512 + (q4*16 + m)*8);
      #pragma unroll
      for (int pt = 0; pt < 4; ++pt)
        acc[rt][pt] = __builtin_amdgcn_mfma_f32_16x16x32_bf16(af, bfr[pt], acc[rt][pt], 0, 0, 0);
    }
  }
  // finalize s (per px)
  ssqL[cg_st*64 + px_st] = ssq;
  __syncthreads();
  if (t < 64){
    float tot = ssqL[t] + ssqL[64 + t] + ssqL[128 + t] + ssqL[192 + t];
    sL[t] = 16.0f / fmaxf(sqrtf(tot), 1e-12f);
  }
  __syncthreads();   // sL ready; MFMA reads of Ab/Xb done -> Pb/Vb writable
  float sv[4];
  #pragma unroll
  for (int pt = 0; pt < 4; ++pt) sv[pt] = sL[pt*16 + m];
  #pragma unroll
  for (int pr = 0; pr < 3; ++pr){
    const int ra = 2*pr, rb = 2*pr + 1;
    const int row0 = wv*96 + pr*32;
    const int type = row0 >> 7;          // 0=q, 1=k, 2=v
    if (type == 0){
      const int slice = row0 >> 5;       // head = q k-slice
      const int j0 = (q4 & 1)*4;
      #pragma unroll
      for (int pt = 0; pt < 4; ++pt){
        float va[4], vb[4];
        float mx = -1e30f;
        #pragma unroll
        for (int r = 0; r < 4; ++r){
          va[r] = acc[ra][pt][r]*sv[pt];
          vb[r] = acc[rb][pt][r]*sv[pt];
          mx = fmaxf(mx, fmaxf(va[r], vb[r]));
        }
        mx = fmaxf(mx, __shfl_xor(mx, 16, 64));
        mx = fmaxf(mx, __shfl_xor(mx, 32, 64));
        float se = 0.f;
        #pragma unroll
        for (int r = 0; r < 4; ++r){
          va[r] = __expf(va[r] - mx); vb[r] = __expf(vb[r] - mx);
          se += va[r] + vb[r];
        }
        se += __shfl_xor(se, 16, 64);
        se += __shfl_xor(se, 32, 64);
        const float inv = QSCALE / se;
        // qpack (B-frag order) into dout rows c' of own px cols:
        // c' = (slice*4 + pt)*4 + q4k;  slot = [m 16][j 8] bf16 (256 B)
        alignas(8) bf16 pka[4], pkb[4];
        #pragma unroll
        for (int r = 0; r < 4; ++r){
          pka[r] = __float2bfloat16(va[r]*inv);
          pkb[r] = __float2bfloat16(vb[r]*inv);
        }
        const int ca = (slice*4 + pt)*4 + (q4 >> 1);
        const int cb = ca + 2;
        bf16* pa = (bf16*)(dout + (size_t)(b*NC + ca)*NPIX + pb) + m*8 + j0;
        bf16* pv = (bf16*)(dout + (size_t)(b*NC + cb)*NPIX + pb) + m*8 + j0;
        *(uint2*)pa = *(const uint2*)pka;
        *(uint2*)pv = *(const uint2*)pkb;
      }
    } else if (type == 1){
      const int d0 = row0 - 128;
      float za[4] = {}, zb[4] = {};
      #pragma unroll
      for (int pt = 0; pt < 4; ++pt){
        #pragma unroll
        for (int r = 0; r < 4; ++r){
          float pa = __expf(acc[ra][pt][r]*sv[pt]);
          float pv = __expf(acc[rb][pt][r]*sv[pt]);
          za[r] += pa; zb[r] += pv;
          Pb[d0      + q4*4 + r][pt*16 + m] = __float2bfloat16(pa);
          Pb[d0 + 16 + q4*4 + r][pt*16 + m] = __float2bfloat16(pv);
        }
      }
      #pragma unroll
      for (int r = 0; r < 4; ++r){
        #pragma unroll
        for (int o = 1; o < 16; o <<= 1){
          za[r] += __shfl_xor(za[r], o, 64);
          zb[r] += __shfl_xor(zb[r], o, 64);
        }
      }
      if (m == 0){
        #pragma unroll
        for (int r = 0; r < 4; ++r){
          atomicAdd(&zacc[b*NHID + d0      + q4*4 + r], za[r]);
          atomicAdd(&zacc[b*NHID + d0 + 16 + q4*4 + r], zb[r]);
        }
      }
    } else {
      const int v0 = row0 - 256;
      #pragma unroll
      for (int pt = 0; pt < 4; ++pt)
        #pragma unroll
        for (int r = 0; r < 4; ++r){
          Vb[v0      + q4*4 + r][pt*16 + m] = __float2bfloat16(acc[ra][pt][r]*sv[pt]);
          Vb[v0 + 16 + q4*4 + r][pt*16 + m] = __float2bfloat16(acc[rb][pt][r]*sv[pt]);
        }
    }
  }
  __syncthreads();
  // ctx MFMA: wave wv = head wv; 64 toks in 2 K-steps
  floatx4 cx[2][2] = {};
  #pragma unroll
  for (int k0t = 0; k0t < 64; k0t += 32){
    bf16x8 af[2], bf[2];
    #pragma unroll
    for (int dt = 0; dt < 2; ++dt) af[dt] = *(const bf16x8*)&Pb[wv*32 + dt*16 + m][k0t + q4*8];
    #pragma unroll
    for (int et = 0; et < 2; ++et) bf[et] = *(const bf16x8*)&Vb[wv*32 + et*16 + m][k0t + q4*8];
    #pragma unroll
    for (int dt = 0; dt < 2; ++dt)
      #pragma unroll
      for (int et = 0; et < 2; ++et)
        cx[dt][et] = __builtin_amdgcn_mfma_f32_16x16x32_bf16(af[dt], bf[et], cx[dt][et], 0, 0, 0);
  }
  float* cb2 = ctxu + (size_t)(b*NH + wv)*ND*ND;
  #pragma unroll
  for (int dt = 0; dt < 2; ++dt)
    #pragma unroll
    for (int et = 0; et < 2; ++et)
      #pragma unroll
      for (int r = 0; r < 4; ++r)
        atomicAdd(&cb2[(dt*16 + q4*4 + r)*ND + et*16 + m], cx[dt][et][r]);
}

// ---------------- K4: Weff -> bf16, packed in MFMA A-frag tile order for k5.
// element (b,o,hd): slice=hd>>5, tile=o>>4, q4k=(hd>>3)&3, m=o&15, j=hd&7
__launch_bounds__(256)
__global__ void k4_weff(const float* __restrict__ ctxu, const float* __restrict__ zacc,
                        const float* __restrict__ memkv, const float* __restrict__ wout,
                        bf16* __restrict__ wpack){
  const int idx = blockIdx.x*256 + threadIdx.x;   // (b*256 + o)*128 + hd
  const int b   = idx >> 15;
  const int o   = (idx >> 7) & 255;
  const int hd  = idx & 127;
  const int h = hd >> 5, d = hd & 31;
  const float* mk = memkv + hd*NMEM;                       // mem_kv[0][h][d][j]
  float me[4];
  float z = zacc[b*NHID + hd];
  #pragma unroll
  for (int j = 0; j < 4; ++j){ me[j] = __expf(mk[j]); z += me[j]; }
  const float invz = 1.0f / z;
  const float* cp = ctxu + (size_t)((b*NH + h)*ND + d)*ND;
  const float* wp = wout + (size_t)o*NHID + h*ND;
  const float* mv = memkv + (size_t)(NHID + h*ND)*NMEM;    // mem_kv[1][h][e][j]
  float acc = 0.f;
  #pragma unroll
  for (int e = 0; e < ND; ++e){
    float ce = cp[e];
    #pragma unroll
    for (int j = 0; j < 4; ++j) ce += me[j]*mv[e*NMEM + j];
    acc += ce*wp[e];
  }
  const int slice = hd >> 5, q4k = (hd >> 3) & 3, j = hd & 7;
  const int tile = o >> 4, m16 = o & 15;
  wpack[((size_t)((b*4 + slice)*16 + tile)*64 + q4k*16 + m16)*8 + j] = __float2bfloat16(acc*invz);
}

// ---------------- K5: MFMA y = Weff @ q_s + bias -> RMSNorm -> dout rows 0..255.
// Both operands DMA-staged (wpack frag-order; qpack from dout rows 0..63 of own cols).
__launch_bounds__(256)
__global__ void k5_out(float* dout, const bf16* __restrict__ wpack,
                       const float* __restrict__ bout, const float* __restrict__ gout){
  __shared__ char smem alignas(16) [21760];
  bf16* Wb = (bf16*)smem;                 // 16 tiles x 1KB = 16384
  bf16* Qb = (bf16*)(smem + 16384);       // 4 tiles x 1KB = 4096
  float* red = (float*)(smem + 20480);    // [4][64]
  float* nf  = (float*)(smem + 21504);    // [64]
  const int t = threadIdx.x;
  const int pb = blockIdx.x * 64, b = blockIdx.y;
  const int wv = t >> 6, lane = t & 63, m = lane & 15, q4 = lane >> 4;
  floatx4 acc[4][4] = {};
  for (int s = 0; s < 4; ++s){
    __syncthreads();   // prev MFMA done
    {  // DMA Wb: wave wv loads its 4 tiles (rows wv*64..+64)
      const bf16* gt = wpack + ((size_t)((b*4 + s)*16 + wv*4)*64 + lane)*8;
      char* lt = smem + wv*4096;
      #pragma unroll
      for (int tt = 0; tt < 4; ++tt)
        dma16(gt + tt*512, lt + tt*1024);
    }
    {  // DMA Qb: wave wv loads px-tile wv; lane l -> row c'=(s*4+wv)*4+(l>>4)
      const char* gq = (const char*)(dout + (size_t)(b*NC + (s*4 + wv)*4 + q4)*NPIX + pb) + m*16;
      dma16(gq, smem + 16384 + wv*1024);
    }
    __syncthreads();   // vmcnt drain
    bf16x8 bfr[4];
    #pragma unroll
    for (int pt = 0; pt < 4; ++pt)
      bfr[pt] = *(const bf16x8*)(Qb + pt*512 + (q4*16 + m)*8);
    #pragma unroll
    for (int rt = 0; rt < 4; ++rt){
      bf16x8 af = *(const bf16x8*)(Wb + (size_t)(wv*4 + rt)*512 + (q4*16 + m)*8);
      #pragma unroll
      for (int pt = 0; pt < 4; ++pt)
        acc[rt][pt] = __builtin_amdgcn_mfma_f32_16x16x32_bf16(af, bfr[pt], acc[rt][pt], 0, 0, 0);
    }
  }
  // bias + ssq partials
  float ps[4] = {0.f, 0.f, 0.f, 0.f};
  #pragma unroll
  for (int rt = 0; rt < 4; ++rt){
    const int row = wv*64 + rt*16 + q4*4;
    #pragma unroll
    for (int r = 0; r < 4; ++r){
      const float bias = bout[row + r];
      #pragma unroll
      for (int pt = 0; pt < 4; ++pt){
        acc[rt][pt][r] += bias;
        ps[pt] += acc[rt][pt][r]*acc[rt][pt][r];
      }
    }
  }
  #pragma unroll
  for (int pt = 0; pt < 4; ++pt){
    ps[pt] += __shfl_xor(ps[pt], 16, 64);
    ps[pt] += __shfl_xor(ps[pt], 32, 64);
  }
  __syncthreads();   // MFMA reads done; reuse smem for reduction
  if (q4 == 0){
    #pragma unroll
    for (int pt = 0; pt < 4; ++pt) red[wv*64 + pt*16 + m] = ps[pt];
  }
  __syncthreads();
  if (t < 64){
    float tot = red[t] + red[64 + t] + red[128 + t] + red[192 + t];
    nf[t] = 16.0f / fmaxf(sqrtf(tot), 1e-12f);
  }
  __syncthreads();
  float nv[4];
  #pragma unroll
  for (int pt = 0; pt < 4; ++pt) nv[pt] = nf[pt*16 + m];
  #pragma unroll
  for (int rt = 0; rt < 4; ++rt){
    const int row = wv*64 + rt*16 + q4*4;
    #pragma unroll
    for (int r = 0; r < 4; ++r){
      const float gg = gout[row + r];
      float* op = dout + (size_t)(b*NC + row + r)*NPIX + pb + m;
      #pragma unroll
      for (int pt = 0; pt < 4; ++pt)
        op[pt*16] = acc[rt][pt][r]*nv[pt]*gg;
    }
  }
}

extern "C" void kernel_launch(void* const* d_in, const int* in_sizes, int n_in,
                              void* d_out, int out_size, void* d_ws, size_t ws_size,
                              hipStream_t stream) {
  (void)in_sizes; (void)n_in; (void)out_size; (void)ws_size;
  const float* x     = (const float*)d_in[0];
  const float* ng    = (const float*)d_in[1];
  const float* wqkv  = (const float*)d_in[2];
  const float* memkv = (const float*)d_in[3];
  const float* wout  = (const float*)d_in[4];
  const float* bout  = (const float*)d_in[5];
  const float* gout  = (const float*)d_in[6];
  float* dout = (float*)d_out;
  char* ws = (char*)d_ws;
  // workspace layout — total 1,515,520 B (~1.45 MB)
  bf16*  wgpack = (bf16*)(ws);              // 8*24*64*8*2  = 196608
  bf16*  wpack  = (bf16*)(ws + 196608);     // 16*4*16*64*8*2 = 1048576
  float* ctxu   = (float*)(ws + 1245184);   // 16*4*32*32*4 = 262144
  float* zacc   = (float*)(ws + 1507328);   // 16*128*4     = 8192

  k0_zero<<<dim3(264),     256, 0, stream>>>(ctxu, 65536 + 2048);
  kW     <<<dim3(48),      256, 0, stream>>>(wqkv, ng, wgpack);
  kA     <<<dim3(64, 16),  256, 0, stream>>>(x, wgpack, dout, ctxu, zacc);
  k4_weff<<<dim3(2048),    256, 0, stream>>>(ctxu, zacc, memkv, wout, wpack);
  k5_out <<<dim3(64, 16),  256, 0, stream>>>(dout, wpack, bout, gout);
}